// Round 10
// baseline (765.710 us; speedup 1.0000x reference)
//
#include <hip/hip_runtime.h>
#include <hip/hip_bf16.h>

#define HID 768
#define DW  200
#define NW  5

// ===========================================================================
// Structure (all fp32; 2.1x-FLOP-reduced algebra from R2, TH-in-registers):
//   G   = attn_W @ W2^T          [768,768]   (gw_kernel, tiny)
//   P2  = LO @ G                 [8192,768]  (proj_kernel)
//   fused_kernel (per block: 8 tokens = 2 groups x 4 tokens):
//     per group g:
//       p2v[4][3] (regs) <- direct L2 loads, issued BEFORE MLP1 (prefetch)
//       th[20][3] (regs) = tanh(WE_tile @ W1 + b1)     <- never hits HBM
//       scores[t,n] = th . p2v  (reg FMA + shuffle reduce)
//       attn = masked softmax (N=5)
//       athT[:, g*4+tt] = sum_n attn*th                -> LDS [768][8]
//     GEMM2: acc = athT @ W2   (24 FMA : 3 L2 loads)
//     out = LN(acc + b2 + LO) * gamma + beta
// R9 post-mortem: p2s LDS tile had ZERO reuse (each elem read once) and its
// 12 KB pushed the block to 53.8 KB -> only 2 blocks/CU (22% occ, latency-
// bound at 40% idle). Dropped -> 41.3 KB -> 3 blocks/CU. tanhf -> fast exp
// form (~8 ops vs ~25).
// ===========================================================================

__device__ __forceinline__ float fast_tanh(float x) {
    float ax = fabsf(x);
    float z  = __expf(-2.0f * ax);
    float r  = (1.0f - z) * __builtin_amdgcn_rcpf(1.0f + z);
    return copysignf(r, x);
}

// ---------------------------------------------------------------------------
// Kernel B: G[d,h] = sum_e attn_W[d,e] * W2[h,e]  (NT GEMM, 768^3, tiny).
// ---------------------------------------------------------------------------
__global__ __launch_bounds__(256)
void gw_kernel(const float* __restrict__ A,
               const float* __restrict__ W2,
               float* __restrict__ G)
{
    __shared__ __align__(16) float AsT[32][68];
    __shared__ __align__(16) float WsT[32][68];
    const int tid = threadIdx.x;
    const int bd = blockIdx.x / (HID / 64), bh = blockIdx.x % (HID / 64);
    const int d0 = bd * 64, h0 = bh * 64;
    const int tx = tid % 16, ty = tid / 16;

    float acc[4][4];
    #pragma unroll
    for (int i = 0; i < 4; ++i)
        #pragma unroll
        for (int j = 0; j < 4; ++j) acc[i][j] = 0.f;

    for (int e0 = 0; e0 < HID; e0 += 32) {
        __syncthreads();
        #pragma unroll
        for (int q = 0; q < 2; ++q) {
            int idx = q * 256 + tid;
            int r = idx / 8, c4 = idx % 8;
            float4 va = *reinterpret_cast<const float4*>(&A [(size_t)(d0 + r) * HID + e0 + c4 * 4]);
            AsT[c4 * 4 + 0][r] = va.x; AsT[c4 * 4 + 1][r] = va.y;
            AsT[c4 * 4 + 2][r] = va.z; AsT[c4 * 4 + 3][r] = va.w;
            float4 vw = *reinterpret_cast<const float4*>(&W2[(size_t)(h0 + r) * HID + e0 + c4 * 4]);
            WsT[c4 * 4 + 0][r] = vw.x; WsT[c4 * 4 + 1][r] = vw.y;
            WsT[c4 * 4 + 2][r] = vw.z; WsT[c4 * 4 + 3][r] = vw.w;
        }
        __syncthreads();
        #pragma unroll 4
        for (int e = 0; e < 32; ++e) {
            float4 a4 = *reinterpret_cast<const float4*>(&AsT[e][ty * 4]);
            float4 b4 = *reinterpret_cast<const float4*>(&WsT[e][tx * 4]);
            float av[4] = {a4.x, a4.y, a4.z, a4.w};
            float bv[4] = {b4.x, b4.y, b4.z, b4.w};
            #pragma unroll
            for (int i = 0; i < 4; ++i)
                #pragma unroll
                for (int j = 0; j < 4; ++j)
                    acc[i][j] = fmaf(av[i], bv[j], acc[i][j]);
        }
    }
    #pragma unroll
    for (int i = 0; i < 4; ++i) {
        float4 o = {acc[i][0], acc[i][1], acc[i][2], acc[i][3]};
        *reinterpret_cast<float4*>(&G[(size_t)(d0 + ty * 4 + i) * HID + h0 + tx * 4]) = o;
    }
}

// ---------------------------------------------------------------------------
// Kernel C: P2 = LO @ G. 8 tokens/block.
// ---------------------------------------------------------------------------
template<int TT>
__global__ __launch_bounds__(256)
void proj_kernel(const float* __restrict__ LO,
                 const float* __restrict__ G,
                 float* __restrict__ P2)
{
    __shared__ __align__(16) float loT[HID][TT];
    const int tid = threadIdx.x;
    const long tok0 = (long)blockIdx.x * TT;

    {
        const float4* src = reinterpret_cast<const float4*>(LO + tok0 * HID);
        for (int i = tid; i < TT * (HID / 4); i += 256) {
            int t = i / (HID / 4), k4 = i % (HID / 4);
            float4 v = src[(size_t)t * (HID / 4) + k4];
            loT[k4 * 4 + 0][t] = v.x; loT[k4 * 4 + 1][t] = v.y;
            loT[k4 * 4 + 2][t] = v.z; loT[k4 * 4 + 3][t] = v.w;
        }
    }
    __syncthreads();

    float acc[TT][3];
    #pragma unroll
    for (int t = 0; t < TT; ++t) { acc[t][0] = 0.f; acc[t][1] = 0.f; acc[t][2] = 0.f; }

    #pragma unroll 2
    for (int k = 0; k < HID; ++k) {
        float a[TT];
        #pragma unroll
        for (int q = 0; q < TT / 4; ++q) {
            float4 v = *reinterpret_cast<const float4*>(&loT[k][q * 4]);
            a[q * 4 + 0] = v.x; a[q * 4 + 1] = v.y; a[q * 4 + 2] = v.z; a[q * 4 + 3] = v.w;
        }
        float w0 = G[(size_t)k * HID + tid];
        float w1 = G[(size_t)k * HID + 256 + tid];
        float w2 = G[(size_t)k * HID + 512 + tid];
        #pragma unroll
        for (int t = 0; t < TT; ++t) {
            acc[t][0] = fmaf(a[t], w0, acc[t][0]);
            acc[t][1] = fmaf(a[t], w1, acc[t][1]);
            acc[t][2] = fmaf(a[t], w2, acc[t][2]);
        }
    }

    #pragma unroll
    for (int c = 0; c < 3; ++c)
        #pragma unroll
        for (int t = 0; t < TT; ++t)
            P2[(tok0 + t) * HID + c * 256 + tid] = acc[t][c];
}

// ---------------------------------------------------------------------------
// Kernel D (fused): MLP1-in-regs + scores + softmax + ATH + GEMM2 + LN.
// 8 tokens/block in 2 groups of 4. LDS ~= 41.3 KB -> 3 blocks/CU.
// ---------------------------------------------------------------------------
__global__ __launch_bounds__(256)
void fused_kernel(const float* __restrict__ WE,
                  const float* __restrict__ W1,
                  const float* __restrict__ b1,
                  const float* __restrict__ W2,
                  const float* __restrict__ b2,
                  const float* __restrict__ LO,
                  const float* __restrict__ P2,
                  const int* __restrict__ mask,
                  const float* __restrict__ gamma,
                  const float* __restrict__ beta,
                  float* __restrict__ out)
{
    __shared__ __align__(16) float weT[DW * 20];     // 16000 B, [k][r] r=0..19
    __shared__ __align__(16) float athT[HID * 8];    // 24576 B, [k][token 0..7]
    __shared__ float red[4][32];
    __shared__ float sc_s[4][NW];
    __shared__ float at_s[4][NW];
    __shared__ float mus[8], rss[8];

    const int tid = threadIdx.x;
    const int wave = tid >> 6, lane = tid & 63;
    const long tok0 = (long)blockIdx.x * 8;

    #pragma unroll 1
    for (int g = 0; g < 2; ++g) {
        const long tokg = tok0 + g * 4;
        const long rowg = tokg * NW;     // 20 word-rows for this group

        // ---- P2 prefetch: direct coalesced L2 loads (read-once; no reuse,
        // so no LDS). Issued before the k-loop -> latency hidden by MLP1. ----
        float p2v[4][3];
        #pragma unroll
        for (int tt = 0; tt < 4; ++tt) {
            p2v[tt][0] = P2[(tokg + tt) * HID + tid];
            p2v[tt][1] = P2[(tokg + tt) * HID + 256 + tid];
            p2v[tt][2] = P2[(tokg + tt) * HID + 512 + tid];
        }

        __syncthreads();   // previous group done with weT before restage

        // ---- stage WE tile transposed ([k][r]) ----
        for (int i = tid; i < 20 * (DW / 4); i += 256) {
            int r = i / (DW / 4), k4 = i % (DW / 4);
            float4 v = *reinterpret_cast<const float4*>(&WE[(rowg + r) * DW + k4 * 4]);
            weT[(k4 * 4 + 0) * 20 + r] = v.x;
            weT[(k4 * 4 + 1) * 20 + r] = v.y;
            weT[(k4 * 4 + 2) * 20 + r] = v.z;
            weT[(k4 * 4 + 3) * 20 + r] = v.w;
        }
        __syncthreads();

        // ---- MLP1: th[r][c] over this thread's 3 columns j = c*256+tid ----
        float th[20][3];
        #pragma unroll
        for (int r = 0; r < 20; ++r) { th[r][0] = 0.f; th[r][1] = 0.f; th[r][2] = 0.f; }

        #pragma unroll 2
        for (int k = 0; k < DW; ++k) {
            float a[20];
            #pragma unroll
            for (int q = 0; q < 5; ++q) {
                float4 v = *reinterpret_cast<const float4*>(&weT[k * 20 + q * 4]);
                a[q * 4 + 0] = v.x; a[q * 4 + 1] = v.y; a[q * 4 + 2] = v.z; a[q * 4 + 3] = v.w;
            }
            float w0 = W1[(size_t)k * HID + tid];
            float w1 = W1[(size_t)k * HID + 256 + tid];
            float w2 = W1[(size_t)k * HID + 512 + tid];
            #pragma unroll
            for (int r = 0; r < 20; ++r) {
                th[r][0] = fmaf(a[r], w0, th[r][0]);
                th[r][1] = fmaf(a[r], w1, th[r][1]);
                th[r][2] = fmaf(a[r], w2, th[r][2]);
            }
        }
        {
            float bb0 = b1[tid], bb1 = b1[256 + tid], bb2 = b1[512 + tid];
            #pragma unroll
            for (int r = 0; r < 20; ++r) {
                th[r][0] = fast_tanh(th[r][0] + bb0);
                th[r][1] = fast_tanh(th[r][1] + bb1);
                th[r][2] = fast_tanh(th[r][2] + bb2);
            }
        }

        // ---- scores: s[tt][n] = sum_j th*p2v ; shuffle + cross-wave reduce ----
        #pragma unroll
        for (int tt = 0; tt < 4; ++tt)
            #pragma unroll
            for (int n = 0; n < NW; ++n) {
                int r = tt * NW + n;
                float s = th[r][0] * p2v[tt][0];
                s = fmaf(th[r][1], p2v[tt][1], s);
                s = fmaf(th[r][2], p2v[tt][2], s);
                #pragma unroll
                for (int off = 32; off; off >>= 1) s += __shfl_xor(s, off);
                if (lane == 0) red[wave][r] = s;
            }
        __syncthreads();
        if (tid < 20) {
            float s = red[0][tid] + red[1][tid] + red[2][tid] + red[3][tid];
            sc_s[tid / NW][tid % NW] = s;
        }
        __syncthreads();

        // ---- masked softmax over N=5 ----
        if (tid < 4) {
            float v[NW]; float m = -3.0e38f;
            #pragma unroll
            for (int n = 0; n < NW; ++n) {
                float sv = (mask[(tokg + tid) * NW + n] != 0) ? -1.0e9f : sc_s[tid][n];
                v[n] = sv; m = fmaxf(m, sv);
            }
            float sum = 0.f;
            #pragma unroll
            for (int n = 0; n < NW; ++n) { float e = expf(v[n] - m); v[n] = e; sum += e; }
            float inv = 1.0f / sum;
            #pragma unroll
            for (int n = 0; n < NW; ++n) at_s[tid][n] = v[n] * inv;
        }
        __syncthreads();

        // ---- ATH (registers) -> athT[k][g*4+tt] ----
        #pragma unroll
        for (int tt = 0; tt < 4; ++tt) {
            float a0 = 0.f, a1 = 0.f, a2 = 0.f;
            #pragma unroll
            for (int n = 0; n < NW; ++n) {
                float w = at_s[tt][n];
                a0 = fmaf(w, th[tt * NW + n][0], a0);
                a1 = fmaf(w, th[tt * NW + n][1], a1);
                a2 = fmaf(w, th[tt * NW + n][2], a2);
            }
            int col = g * 4 + tt;
            athT[(0 * 256 + tid) * 8 + col] = a0;
            athT[(1 * 256 + tid) * 8 + col] = a1;
            athT[(2 * 256 + tid) * 8 + col] = a2;
        }
    }
    __syncthreads();

    // ---- GEMM2: acc[t][c] = sum_k athT[k][t] * W2[k][j] ----
    float acc[8][3];
    #pragma unroll
    for (int t = 0; t < 8; ++t) { acc[t][0] = 0.f; acc[t][1] = 0.f; acc[t][2] = 0.f; }

    #pragma unroll 4
    for (int k = 0; k < HID; ++k) {
        float4 a0 = *reinterpret_cast<const float4*>(&athT[k * 8]);
        float4 a1 = *reinterpret_cast<const float4*>(&athT[k * 8 + 4]);
        float w0 = W2[(size_t)k * HID + tid];
        float w1 = W2[(size_t)k * HID + 256 + tid];
        float w2 = W2[(size_t)k * HID + 512 + tid];
        acc[0][0] = fmaf(a0.x, w0, acc[0][0]); acc[0][1] = fmaf(a0.x, w1, acc[0][1]); acc[0][2] = fmaf(a0.x, w2, acc[0][2]);
        acc[1][0] = fmaf(a0.y, w0, acc[1][0]); acc[1][1] = fmaf(a0.y, w1, acc[1][1]); acc[1][2] = fmaf(a0.y, w2, acc[1][2]);
        acc[2][0] = fmaf(a0.z, w0, acc[2][0]); acc[2][1] = fmaf(a0.z, w1, acc[2][1]); acc[2][2] = fmaf(a0.z, w2, acc[2][2]);
        acc[3][0] = fmaf(a0.w, w0, acc[3][0]); acc[3][1] = fmaf(a0.w, w1, acc[3][1]); acc[3][2] = fmaf(a0.w, w2, acc[3][2]);
        acc[4][0] = fmaf(a1.x, w0, acc[4][0]); acc[4][1] = fmaf(a1.x, w1, acc[4][1]); acc[4][2] = fmaf(a1.x, w2, acc[4][2]);
        acc[5][0] = fmaf(a1.y, w0, acc[5][0]); acc[5][1] = fmaf(a1.y, w1, acc[5][1]); acc[5][2] = fmaf(a1.y, w2, acc[5][2]);
        acc[6][0] = fmaf(a1.z, w0, acc[6][0]); acc[6][1] = fmaf(a1.z, w1, acc[6][1]); acc[6][2] = fmaf(a1.z, w2, acc[6][2]);
        acc[7][0] = fmaf(a1.w, w0, acc[7][0]); acc[7][1] = fmaf(a1.w, w1, acc[7][1]); acc[7][2] = fmaf(a1.w, w2, acc[7][2]);
    }

    // ---- + b2 + LO residual ----
    float v[8][3];
    {
        float bb0 = b2[tid], bb1 = b2[256 + tid], bb2 = b2[512 + tid];
        #pragma unroll
        for (int t = 0; t < 8; ++t) {
            v[t][0] = acc[t][0] + bb0 + LO[(tok0 + t) * HID + tid];
            v[t][1] = acc[t][1] + bb1 + LO[(tok0 + t) * HID + 256 + tid];
            v[t][2] = acc[t][2] + bb2 + LO[(tok0 + t) * HID + 512 + tid];
        }
    }

    // ---- LayerNorm reductions (sum, sumsq per token) ----
    #pragma unroll
    for (int t = 0; t < 8; ++t) {
        float s = v[t][0] + v[t][1] + v[t][2];
        float q = v[t][0] * v[t][0];
        q = fmaf(v[t][1], v[t][1], q);
        q = fmaf(v[t][2], v[t][2], q);
        #pragma unroll
        for (int off = 32; off; off >>= 1) { s += __shfl_xor(s, off); q += __shfl_xor(q, off); }
        if (lane == 0) { red[wave][t] = s; red[wave][8 + t] = q; }
    }
    __syncthreads();
    if (tid < 8) {
        float S = red[0][tid] + red[1][tid] + red[2][tid] + red[3][tid];
        float Q = red[0][8 + tid] + red[1][8 + tid] + red[2][8 + tid] + red[3][8 + tid];
        float mu = S * (1.0f / HID);
        float var = Q * (1.0f / HID) - mu * mu;
        mus[tid] = mu;
        rss[tid] = rsqrtf(var + 1e-12f);
    }
    __syncthreads();

    {
        float g0 = gamma[tid], g1 = gamma[256 + tid], g2 = gamma[512 + tid];
        float e0 = beta[tid],  e1 = beta[256 + tid],  e2 = beta[512 + tid];
        #pragma unroll
        for (int t = 0; t < 8; ++t) {
            float mu = mus[t], rs = rss[t];
            out[(tok0 + t) * HID + tid]       = (v[t][0] - mu) * rs * g0 + e0;
            out[(tok0 + t) * HID + 256 + tid] = (v[t][1] - mu) * rs * g1 + e1;
            out[(tok0 + t) * HID + 512 + tid] = (v[t][2] - mu) * rs * g2 + e2;
        }
    }
}

// ---------------------------------------------------------------------------
extern "C" void kernel_launch(void* const* d_in, const int* in_sizes, int n_in,
                              void* d_out, int out_size, void* d_ws, size_t ws_size,
                              hipStream_t stream)
{
    const float* LO    = (const float*)d_in[0];  // [16,512,768]
    const float* WE    = (const float*)d_in[1];  // [16,512,5,200]
    const int*   mask  = (const int*)  d_in[2];  // [16,512,5]
    const float* W1    = (const float*)d_in[3];  // [200,768]
    const float* b1    = (const float*)d_in[4];  // [768]
    const float* W2    = (const float*)d_in[5];  // [768,768]
    const float* b2    = (const float*)d_in[6];  // [768]
    const float* attnW = (const float*)d_in[7];  // [768,768]
    const float* gamma = (const float*)d_in[8];  // [768]
    const float* beta  = (const float*)d_in[9];  // [768]
    float* out = (float*)d_out;                  // [16,512,768]

    const int T = 16 * 512;  // 8192 tokens

    // workspace (floats): P2 [T,768] | G [768,768]   (~27.6 MB)
    float* P2 = (float*)d_ws;
    float* G  = P2 + (size_t)T * HID;

    gw_kernel<<<(HID / 64) * (HID / 64), 256, 0, stream>>>(attnW, W2, G);
    proj_kernel<8><<<T / 8, 256, 0, stream>>>(LO, G, P2);
    fused_kernel<<<T / 8, 256, 0, stream>>>(WE, W1, b1, W2, b2, LO, P2, mask, gamma, beta, out);
}

// Round 11
// 704.736 us; speedup vs baseline: 1.0865x; 1.0865x over previous
//
#include <hip/hip_runtime.h>
#include <hip/hip_bf16.h>

#define HID 768
#define DW  200
#define NW  5

// ===========================================================================
// R10 post-mortem: LDS was not the occupancy limiter (R9's 53.8KB already fit
// 3 blocks); pre-barrier P2 "prefetch" serialized on the compiler's
// vmcnt(0)-before-s_barrier drain -> 446->526 regression. This round: raise
// TLP structurally. One group of 4 tokens per block -> 2048 blocks,
// LDS ~29KB, __launch_bounds__(256,5) -> 5 blocks/CU (VGPR cap 102, measured
// live-set 76). P2 direct loads issued AFTER the weT barrier so they overlap
// MLP1 legitimately. fast_tanh kept.
//   G   = attn_W @ W2^T          (gw_kernel)
//   P2  = LO @ G                 (proj_kernel)
//   fused: th[20][3](regs)=tanh(WE@W1+b1); scores=th.p2v; softmax;
//          athT[768][4](LDS, 16B rows); GEMM2 athT@W2; +LO; LayerNorm.
// ===========================================================================

__device__ __forceinline__ float fast_tanh(float x) {
    float ax = fabsf(x);
    float z  = __expf(-2.0f * ax);
    float r  = (1.0f - z) * __builtin_amdgcn_rcpf(1.0f + z);
    return copysignf(r, x);
}

// ---------------------------------------------------------------------------
// Kernel B: G[d,h] = sum_e attn_W[d,e] * W2[h,e]  (NT GEMM, 768^3, tiny).
// ---------------------------------------------------------------------------
__global__ __launch_bounds__(256)
void gw_kernel(const float* __restrict__ A,
               const float* __restrict__ W2,
               float* __restrict__ G)
{
    __shared__ __align__(16) float AsT[32][68];
    __shared__ __align__(16) float WsT[32][68];
    const int tid = threadIdx.x;
    const int bd = blockIdx.x / (HID / 64), bh = blockIdx.x % (HID / 64);
    const int d0 = bd * 64, h0 = bh * 64;
    const int tx = tid % 16, ty = tid / 16;

    float acc[4][4];
    #pragma unroll
    for (int i = 0; i < 4; ++i)
        #pragma unroll
        for (int j = 0; j < 4; ++j) acc[i][j] = 0.f;

    for (int e0 = 0; e0 < HID; e0 += 32) {
        __syncthreads();
        #pragma unroll
        for (int q = 0; q < 2; ++q) {
            int idx = q * 256 + tid;
            int r = idx / 8, c4 = idx % 8;
            float4 va = *reinterpret_cast<const float4*>(&A [(size_t)(d0 + r) * HID + e0 + c4 * 4]);
            AsT[c4 * 4 + 0][r] = va.x; AsT[c4 * 4 + 1][r] = va.y;
            AsT[c4 * 4 + 2][r] = va.z; AsT[c4 * 4 + 3][r] = va.w;
            float4 vw = *reinterpret_cast<const float4*>(&W2[(size_t)(h0 + r) * HID + e0 + c4 * 4]);
            WsT[c4 * 4 + 0][r] = vw.x; WsT[c4 * 4 + 1][r] = vw.y;
            WsT[c4 * 4 + 2][r] = vw.z; WsT[c4 * 4 + 3][r] = vw.w;
        }
        __syncthreads();
        #pragma unroll 4
        for (int e = 0; e < 32; ++e) {
            float4 a4 = *reinterpret_cast<const float4*>(&AsT[e][ty * 4]);
            float4 b4 = *reinterpret_cast<const float4*>(&WsT[e][tx * 4]);
            float av[4] = {a4.x, a4.y, a4.z, a4.w};
            float bv[4] = {b4.x, b4.y, b4.z, b4.w};
            #pragma unroll
            for (int i = 0; i < 4; ++i)
                #pragma unroll
                for (int j = 0; j < 4; ++j)
                    acc[i][j] = fmaf(av[i], bv[j], acc[i][j]);
        }
    }
    #pragma unroll
    for (int i = 0; i < 4; ++i) {
        float4 o = {acc[i][0], acc[i][1], acc[i][2], acc[i][3]};
        *reinterpret_cast<float4*>(&G[(size_t)(d0 + ty * 4 + i) * HID + h0 + tx * 4]) = o;
    }
}

// ---------------------------------------------------------------------------
// Kernel C: P2 = LO @ G. 8 tokens/block (unchanged control).
// ---------------------------------------------------------------------------
template<int TT>
__global__ __launch_bounds__(256)
void proj_kernel(const float* __restrict__ LO,
                 const float* __restrict__ G,
                 float* __restrict__ P2)
{
    __shared__ __align__(16) float loT[HID][TT];
    const int tid = threadIdx.x;
    const long tok0 = (long)blockIdx.x * TT;

    {
        const float4* src = reinterpret_cast<const float4*>(LO + tok0 * HID);
        for (int i = tid; i < TT * (HID / 4); i += 256) {
            int t = i / (HID / 4), k4 = i % (HID / 4);
            float4 v = src[(size_t)t * (HID / 4) + k4];
            loT[k4 * 4 + 0][t] = v.x; loT[k4 * 4 + 1][t] = v.y;
            loT[k4 * 4 + 2][t] = v.z; loT[k4 * 4 + 3][t] = v.w;
        }
    }
    __syncthreads();

    float acc[TT][3];
    #pragma unroll
    for (int t = 0; t < TT; ++t) { acc[t][0] = 0.f; acc[t][1] = 0.f; acc[t][2] = 0.f; }

    #pragma unroll 2
    for (int k = 0; k < HID; ++k) {
        float a[TT];
        #pragma unroll
        for (int q = 0; q < TT / 4; ++q) {
            float4 v = *reinterpret_cast<const float4*>(&loT[k][q * 4]);
            a[q * 4 + 0] = v.x; a[q * 4 + 1] = v.y; a[q * 4 + 2] = v.z; a[q * 4 + 3] = v.w;
        }
        float w0 = G[(size_t)k * HID + tid];
        float w1 = G[(size_t)k * HID + 256 + tid];
        float w2 = G[(size_t)k * HID + 512 + tid];
        #pragma unroll
        for (int t = 0; t < TT; ++t) {
            acc[t][0] = fmaf(a[t], w0, acc[t][0]);
            acc[t][1] = fmaf(a[t], w1, acc[t][1]);
            acc[t][2] = fmaf(a[t], w2, acc[t][2]);
        }
    }

    #pragma unroll
    for (int c = 0; c < 3; ++c)
        #pragma unroll
        for (int t = 0; t < TT; ++t)
            P2[(tok0 + t) * HID + c * 256 + tid] = acc[t][c];
}

// ---------------------------------------------------------------------------
// Kernel D (fused): 4 tokens/block, 2048 blocks, LDS ~29KB -> 5 blocks/CU.
// ---------------------------------------------------------------------------
__global__ __launch_bounds__(256, 5)
void fused_kernel(const float* __restrict__ WE,
                  const float* __restrict__ W1,
                  const float* __restrict__ b1,
                  const float* __restrict__ W2,
                  const float* __restrict__ b2,
                  const float* __restrict__ LO,
                  const float* __restrict__ P2,
                  const int* __restrict__ mask,
                  const float* __restrict__ gamma,
                  const float* __restrict__ beta,
                  float* __restrict__ out)
{
    __shared__ __align__(16) float weT[DW * 20];     // 16000 B, [k][r] r=0..19
    __shared__ __align__(16) float athT[HID * 4];    // 12288 B, [k][token], 16B rows
    __shared__ float red[4][32];
    __shared__ float sc_s[4][NW];
    __shared__ float at_s[4][NW];
    __shared__ float mus[4], rss[4];

    const int tid = threadIdx.x;
    const int wave = tid >> 6, lane = tid & 63;
    const long tok0 = (long)blockIdx.x * 4;
    const long row0 = tok0 * NW;         // 20 word-rows for this block

    // ---- stage WE tile transposed ([k][r]) ----
    for (int i = tid; i < 20 * (DW / 4); i += 256) {
        int r = i / (DW / 4), k4 = i % (DW / 4);
        float4 v = *reinterpret_cast<const float4*>(&WE[(row0 + r) * DW + k4 * 4]);
        weT[(k4 * 4 + 0) * 20 + r] = v.x;
        weT[(k4 * 4 + 1) * 20 + r] = v.y;
        weT[(k4 * 4 + 2) * 20 + r] = v.z;
        weT[(k4 * 4 + 3) * 20 + r] = v.w;
    }
    __syncthreads();

    // ---- P2 direct loads AFTER the barrier: overlap with MLP1 k-loop ----
    float p2v[4][3];
    #pragma unroll
    for (int tt = 0; tt < 4; ++tt) {
        p2v[tt][0] = P2[(tok0 + tt) * HID + tid];
        p2v[tt][1] = P2[(tok0 + tt) * HID + 256 + tid];
        p2v[tt][2] = P2[(tok0 + tt) * HID + 512 + tid];
    }

    // ---- MLP1: th[r][c] over this thread's 3 columns j = c*256+tid ----
    float th[20][3];
    #pragma unroll
    for (int r = 0; r < 20; ++r) { th[r][0] = 0.f; th[r][1] = 0.f; th[r][2] = 0.f; }

    #pragma unroll 2
    for (int k = 0; k < DW; ++k) {
        float a[20];
        #pragma unroll
        for (int q = 0; q < 5; ++q) {
            float4 v = *reinterpret_cast<const float4*>(&weT[k * 20 + q * 4]);
            a[q * 4 + 0] = v.x; a[q * 4 + 1] = v.y; a[q * 4 + 2] = v.z; a[q * 4 + 3] = v.w;
        }
        float w0 = W1[(size_t)k * HID + tid];
        float w1 = W1[(size_t)k * HID + 256 + tid];
        float w2 = W1[(size_t)k * HID + 512 + tid];
        #pragma unroll
        for (int r = 0; r < 20; ++r) {
            th[r][0] = fmaf(a[r], w0, th[r][0]);
            th[r][1] = fmaf(a[r], w1, th[r][1]);
            th[r][2] = fmaf(a[r], w2, th[r][2]);
        }
    }
    {
        float bb0 = b1[tid], bb1 = b1[256 + tid], bb2 = b1[512 + tid];
        #pragma unroll
        for (int r = 0; r < 20; ++r) {
            th[r][0] = fast_tanh(th[r][0] + bb0);
            th[r][1] = fast_tanh(th[r][1] + bb1);
            th[r][2] = fast_tanh(th[r][2] + bb2);
        }
    }

    // ---- scores: s[tt][n] = sum_j th*p2v ; shuffle + cross-wave reduce ----
    #pragma unroll
    for (int tt = 0; tt < 4; ++tt)
        #pragma unroll
        for (int n = 0; n < NW; ++n) {
            int r = tt * NW + n;
            float s = th[r][0] * p2v[tt][0];
            s = fmaf(th[r][1], p2v[tt][1], s);
            s = fmaf(th[r][2], p2v[tt][2], s);
            #pragma unroll
            for (int off = 32; off; off >>= 1) s += __shfl_xor(s, off);
            if (lane == 0) red[wave][r] = s;
        }
    __syncthreads();
    if (tid < 20) {
        float s = red[0][tid] + red[1][tid] + red[2][tid] + red[3][tid];
        sc_s[tid / NW][tid % NW] = s;
    }
    __syncthreads();

    // ---- masked softmax over N=5 ----
    if (tid < 4) {
        float v[NW]; float m = -3.0e38f;
        #pragma unroll
        for (int n = 0; n < NW; ++n) {
            float sv = (mask[(tok0 + tid) * NW + n] != 0) ? -1.0e9f : sc_s[tid][n];
            v[n] = sv; m = fmaxf(m, sv);
        }
        float sum = 0.f;
        #pragma unroll
        for (int n = 0; n < NW; ++n) { float e = expf(v[n] - m); v[n] = e; sum += e; }
        float inv = 1.0f / sum;
        #pragma unroll
        for (int n = 0; n < NW; ++n) at_s[tid][n] = v[n] * inv;
    }
    __syncthreads();

    // ---- ATH (registers) -> athT[k][tt], 16B rows (aligned float4 reads) ----
    #pragma unroll
    for (int tt = 0; tt < 4; ++tt) {
        float a0 = 0.f, a1 = 0.f, a2 = 0.f;
        #pragma unroll
        for (int n = 0; n < NW; ++n) {
            float w = at_s[tt][n];
            a0 = fmaf(w, th[tt * NW + n][0], a0);
            a1 = fmaf(w, th[tt * NW + n][1], a1);
            a2 = fmaf(w, th[tt * NW + n][2], a2);
        }
        athT[(0 * 256 + tid) * 4 + tt] = a0;
        athT[(1 * 256 + tid) * 4 + tt] = a1;
        athT[(2 * 256 + tid) * 4 + tt] = a2;
    }
    __syncthreads();

    // ---- GEMM2: acc[t][c] = sum_k athT[k][t] * W2[k][j] ----
    float acc[4][3];
    #pragma unroll
    for (int t = 0; t < 4; ++t) { acc[t][0] = 0.f; acc[t][1] = 0.f; acc[t][2] = 0.f; }

    #pragma unroll 4
    for (int k = 0; k < HID; ++k) {
        float4 a4 = *reinterpret_cast<const float4*>(&athT[k * 4]);
        float w0 = W2[(size_t)k * HID + tid];
        float w1 = W2[(size_t)k * HID + 256 + tid];
        float w2 = W2[(size_t)k * HID + 512 + tid];
        acc[0][0] = fmaf(a4.x, w0, acc[0][0]); acc[0][1] = fmaf(a4.x, w1, acc[0][1]); acc[0][2] = fmaf(a4.x, w2, acc[0][2]);
        acc[1][0] = fmaf(a4.y, w0, acc[1][0]); acc[1][1] = fmaf(a4.y, w1, acc[1][1]); acc[1][2] = fmaf(a4.y, w2, acc[1][2]);
        acc[2][0] = fmaf(a4.z, w0, acc[2][0]); acc[2][1] = fmaf(a4.z, w1, acc[2][1]); acc[2][2] = fmaf(a4.z, w2, acc[2][2]);
        acc[3][0] = fmaf(a4.w, w0, acc[3][0]); acc[3][1] = fmaf(a4.w, w1, acc[3][1]); acc[3][2] = fmaf(a4.w, w2, acc[3][2]);
    }

    // ---- + b2 + LO residual ----
    float v[4][3];
    {
        float bb0 = b2[tid], bb1 = b2[256 + tid], bb2 = b2[512 + tid];
        #pragma unroll
        for (int t = 0; t < 4; ++t) {
            v[t][0] = acc[t][0] + bb0 + LO[(tok0 + t) * HID + tid];
            v[t][1] = acc[t][1] + bb1 + LO[(tok0 + t) * HID + 256 + tid];
            v[t][2] = acc[t][2] + bb2 + LO[(tok0 + t) * HID + 512 + tid];
        }
    }

    // ---- LayerNorm reductions (sum, sumsq per token) ----
    #pragma unroll
    for (int t = 0; t < 4; ++t) {
        float s = v[t][0] + v[t][1] + v[t][2];
        float q = v[t][0] * v[t][0];
        q = fmaf(v[t][1], v[t][1], q);
        q = fmaf(v[t][2], v[t][2], q);
        #pragma unroll
        for (int off = 32; off; off >>= 1) { s += __shfl_xor(s, off); q += __shfl_xor(q, off); }
        if (lane == 0) { red[wave][t] = s; red[wave][4 + t] = q; }
    }
    __syncthreads();
    if (tid < 4) {
        float S = red[0][tid] + red[1][tid] + red[2][tid] + red[3][tid];
        float Q = red[0][4 + tid] + red[1][4 + tid] + red[2][4 + tid] + red[3][4 + tid];
        float mu = S * (1.0f / HID);
        float var = Q * (1.0f / HID) - mu * mu;
        mus[tid] = mu;
        rss[tid] = rsqrtf(var + 1e-12f);
    }
    __syncthreads();

    {
        float g0 = gamma[tid], g1 = gamma[256 + tid], g2 = gamma[512 + tid];
        float e0 = beta[tid],  e1 = beta[256 + tid],  e2 = beta[512 + tid];
        #pragma unroll
        for (int t = 0; t < 4; ++t) {
            float mu = mus[t], rs = rss[t];
            out[(tok0 + t) * HID + tid]       = (v[t][0] - mu) * rs * g0 + e0;
            out[(tok0 + t) * HID + 256 + tid] = (v[t][1] - mu) * rs * g1 + e1;
            out[(tok0 + t) * HID + 512 + tid] = (v[t][2] - mu) * rs * g2 + e2;
        }
    }
}

// ---------------------------------------------------------------------------
extern "C" void kernel_launch(void* const* d_in, const int* in_sizes, int n_in,
                              void* d_out, int out_size, void* d_ws, size_t ws_size,
                              hipStream_t stream)
{
    const float* LO    = (const float*)d_in[0];  // [16,512,768]
    const float* WE    = (const float*)d_in[1];  // [16,512,5,200]
    const int*   mask  = (const int*)  d_in[2];  // [16,512,5]
    const float* W1    = (const float*)d_in[3];  // [200,768]
    const float* b1    = (const float*)d_in[4];  // [768]
    const float* W2    = (const float*)d_in[5];  // [768,768]
    const float* b2    = (const float*)d_in[6];  // [768]
    const float* attnW = (const float*)d_in[7];  // [768,768]
    const float* gamma = (const float*)d_in[8];  // [768]
    const float* beta  = (const float*)d_in[9];  // [768]
    float* out = (float*)d_out;                  // [16,512,768]

    const int T = 16 * 512;  // 8192 tokens

    // workspace (floats): P2 [T,768] | G [768,768]   (~27.6 MB)
    float* P2 = (float*)d_ws;
    float* G  = P2 + (size_t)T * HID;

    gw_kernel<<<(HID / 64) * (HID / 64), 256, 0, stream>>>(attnW, W2, G);
    proj_kernel<8><<<T / 8, 256, 0, stream>>>(LO, G, P2);
    fused_kernel<<<T / 4, 256, 0, stream>>>(WE, W1, b1, W2, b2, LO, P2, mask, gamma, beta, out);
}

// Round 12
// 693.671 us; speedup vs baseline: 1.1039x; 1.0160x over previous
//
#include <hip/hip_runtime.h>
#include <hip/hip_bf16.h>

#define HID 768
#define DW  200
#define NW  5

// ===========================================================================
// R11 post-mortem: __launch_bounds__(256,5) capped VGPRs at 48 -> the ~60-reg
// th[] live set spilled (WRITE_SIZE 25->55 MB, VALU inflated by spill/shuffle
// traffic). R12: launch_bounds(256,4) (128-reg budget, no spill) and shrink
// LDS to ~13 KB so LDS never caps residency: MLP1 k-loop split into 2 halves
// (WE tile [100][20] = 8 KB) aliased with athT[768][4] (12.3 KB) in one
// union buffer. 4 tokens/block, 2048 blocks, 4 blocks/CU = 16 waves.
//   G   = attn_W @ W2^T          (gw_kernel)
//   P2  = LO @ G                 (proj_kernel)
//   fused: th[20][3](regs)=tanh(WE@W1+b1); scores=th.p2v; softmax;
//          athT(LDS union); GEMM2 athT@W2; +b2+LO; LayerNorm.
// ===========================================================================

__device__ __forceinline__ float fast_tanh(float x) {
    float ax = fabsf(x);
    float z  = __expf(-2.0f * ax);
    float r  = (1.0f - z) * __builtin_amdgcn_rcpf(1.0f + z);
    return copysignf(r, x);
}

// ---------------------------------------------------------------------------
// Kernel B: G[d,h] = sum_e attn_W[d,e] * W2[h,e]  (NT GEMM, 768^3, tiny).
// ---------------------------------------------------------------------------
__global__ __launch_bounds__(256)
void gw_kernel(const float* __restrict__ A,
               const float* __restrict__ W2,
               float* __restrict__ G)
{
    __shared__ __align__(16) float AsT[32][68];
    __shared__ __align__(16) float WsT[32][68];
    const int tid = threadIdx.x;
    const int bd = blockIdx.x / (HID / 64), bh = blockIdx.x % (HID / 64);
    const int d0 = bd * 64, h0 = bh * 64;
    const int tx = tid % 16, ty = tid / 16;

    float acc[4][4];
    #pragma unroll
    for (int i = 0; i < 4; ++i)
        #pragma unroll
        for (int j = 0; j < 4; ++j) acc[i][j] = 0.f;

    for (int e0 = 0; e0 < HID; e0 += 32) {
        __syncthreads();
        #pragma unroll
        for (int q = 0; q < 2; ++q) {
            int idx = q * 256 + tid;
            int r = idx / 8, c4 = idx % 8;
            float4 va = *reinterpret_cast<const float4*>(&A [(size_t)(d0 + r) * HID + e0 + c4 * 4]);
            AsT[c4 * 4 + 0][r] = va.x; AsT[c4 * 4 + 1][r] = va.y;
            AsT[c4 * 4 + 2][r] = va.z; AsT[c4 * 4 + 3][r] = va.w;
            float4 vw = *reinterpret_cast<const float4*>(&W2[(size_t)(h0 + r) * HID + e0 + c4 * 4]);
            WsT[c4 * 4 + 0][r] = vw.x; WsT[c4 * 4 + 1][r] = vw.y;
            WsT[c4 * 4 + 2][r] = vw.z; WsT[c4 * 4 + 3][r] = vw.w;
        }
        __syncthreads();
        #pragma unroll 4
        for (int e = 0; e < 32; ++e) {
            float4 a4 = *reinterpret_cast<const float4*>(&AsT[e][ty * 4]);
            float4 b4 = *reinterpret_cast<const float4*>(&WsT[e][tx * 4]);
            float av[4] = {a4.x, a4.y, a4.z, a4.w};
            float bv[4] = {b4.x, b4.y, b4.z, b4.w};
            #pragma unroll
            for (int i = 0; i < 4; ++i)
                #pragma unroll
                for (int j = 0; j < 4; ++j)
                    acc[i][j] = fmaf(av[i], bv[j], acc[i][j]);
        }
    }
    #pragma unroll
    for (int i = 0; i < 4; ++i) {
        float4 o = {acc[i][0], acc[i][1], acc[i][2], acc[i][3]};
        *reinterpret_cast<float4*>(&G[(size_t)(d0 + ty * 4 + i) * HID + h0 + tx * 4]) = o;
    }
}

// ---------------------------------------------------------------------------
// Kernel C: P2 = LO @ G. 8 tokens/block (unchanged control).
// ---------------------------------------------------------------------------
template<int TT>
__global__ __launch_bounds__(256)
void proj_kernel(const float* __restrict__ LO,
                 const float* __restrict__ G,
                 float* __restrict__ P2)
{
    __shared__ __align__(16) float loT[HID][TT];
    const int tid = threadIdx.x;
    const long tok0 = (long)blockIdx.x * TT;

    {
        const float4* src = reinterpret_cast<const float4*>(LO + tok0 * HID);
        for (int i = tid; i < TT * (HID / 4); i += 256) {
            int t = i / (HID / 4), k4 = i % (HID / 4);
            float4 v = src[(size_t)t * (HID / 4) + k4];
            loT[k4 * 4 + 0][t] = v.x; loT[k4 * 4 + 1][t] = v.y;
            loT[k4 * 4 + 2][t] = v.z; loT[k4 * 4 + 3][t] = v.w;
        }
    }
    __syncthreads();

    float acc[TT][3];
    #pragma unroll
    for (int t = 0; t < TT; ++t) { acc[t][0] = 0.f; acc[t][1] = 0.f; acc[t][2] = 0.f; }

    #pragma unroll 2
    for (int k = 0; k < HID; ++k) {
        float a[TT];
        #pragma unroll
        for (int q = 0; q < TT / 4; ++q) {
            float4 v = *reinterpret_cast<const float4*>(&loT[k][q * 4]);
            a[q * 4 + 0] = v.x; a[q * 4 + 1] = v.y; a[q * 4 + 2] = v.z; a[q * 4 + 3] = v.w;
        }
        float w0 = G[(size_t)k * HID + tid];
        float w1 = G[(size_t)k * HID + 256 + tid];
        float w2 = G[(size_t)k * HID + 512 + tid];
        #pragma unroll
        for (int t = 0; t < TT; ++t) {
            acc[t][0] = fmaf(a[t], w0, acc[t][0]);
            acc[t][1] = fmaf(a[t], w1, acc[t][1]);
            acc[t][2] = fmaf(a[t], w2, acc[t][2]);
        }
    }

    #pragma unroll
    for (int c = 0; c < 3; ++c)
        #pragma unroll
        for (int t = 0; t < TT; ++t)
            P2[(tok0 + t) * HID + c * 256 + tid] = acc[t][c];
}

// ---------------------------------------------------------------------------
// Kernel D (fused): 4 tokens/block, 2048 blocks, LDS ~13 KB, 128-VGPR budget.
// ---------------------------------------------------------------------------
#define KSPLIT 100   // MLP1 k-halves; WE tile = [KSPLIT][20] = 8 KB

__global__ __launch_bounds__(256, 4)
void fused_kernel(const float* __restrict__ WE,
                  const float* __restrict__ W1,
                  const float* __restrict__ b1,
                  const float* __restrict__ W2,
                  const float* __restrict__ b2,
                  const float* __restrict__ LO,
                  const float* __restrict__ P2,
                  const int* __restrict__ mask,
                  const float* __restrict__ gamma,
                  const float* __restrict__ beta,
                  float* __restrict__ out)
{
    // union buffer: phase 1 = weT [KSPLIT][20] (8 KB, re-staged twice);
    //               phase 2 = athT [HID][4]   (12.3 KB). Barrier-separated.
    __shared__ __align__(16) float smem[HID * 4];    // 12288 B
    __shared__ float red[4][32];
    __shared__ float sc_s[4][NW];
    __shared__ float at_s[4][NW];
    __shared__ float mus[4], rss[4];

    const int tid = threadIdx.x;
    const int wave = tid >> 6, lane = tid & 63;
    const long tok0 = (long)blockIdx.x * 4;
    const long row0 = tok0 * NW;         // 20 word-rows for this block

    // ---- P2 direct loads: issued early, consumed after MLP1 (overlap) ----
    float p2v[4][3];
    #pragma unroll
    for (int tt = 0; tt < 4; ++tt) {
        p2v[tt][0] = P2[(tok0 + tt) * HID + tid];
        p2v[tt][1] = P2[(tok0 + tt) * HID + 256 + tid];
        p2v[tt][2] = P2[(tok0 + tt) * HID + 512 + tid];
    }

    // ---- MLP1 in 2 k-halves: th[r][c], j = c*256+tid ----
    float th[20][3];
    #pragma unroll
    for (int r = 0; r < 20; ++r) { th[r][0] = 0.f; th[r][1] = 0.f; th[r][2] = 0.f; }

    #pragma unroll 1
    for (int half = 0; half < 2; ++half) {
        const int kbase = half * KSPLIT;
        __syncthreads();   // previous phase done with smem
        // stage WE[:, kbase..kbase+99] transposed: smem[k'*20 + r]
        for (int i = tid; i < 20 * (KSPLIT / 4); i += 256) {
            int r = i / (KSPLIT / 4), k4 = i % (KSPLIT / 4);
            float4 v = *reinterpret_cast<const float4*>(&WE[(row0 + r) * DW + kbase + k4 * 4]);
            smem[(k4 * 4 + 0) * 20 + r] = v.x;
            smem[(k4 * 4 + 1) * 20 + r] = v.y;
            smem[(k4 * 4 + 2) * 20 + r] = v.z;
            smem[(k4 * 4 + 3) * 20 + r] = v.w;
        }
        __syncthreads();

        #pragma unroll 2
        for (int kk = 0; kk < KSPLIT; ++kk) {
            int k = kbase + kk;
            float a[20];
            #pragma unroll
            for (int q = 0; q < 5; ++q) {
                float4 v = *reinterpret_cast<const float4*>(&smem[kk * 20 + q * 4]);
                a[q * 4 + 0] = v.x; a[q * 4 + 1] = v.y; a[q * 4 + 2] = v.z; a[q * 4 + 3] = v.w;
            }
            float w0 = W1[(size_t)k * HID + tid];
            float w1 = W1[(size_t)k * HID + 256 + tid];
            float w2 = W1[(size_t)k * HID + 512 + tid];
            #pragma unroll
            for (int r = 0; r < 20; ++r) {
                th[r][0] = fmaf(a[r], w0, th[r][0]);
                th[r][1] = fmaf(a[r], w1, th[r][1]);
                th[r][2] = fmaf(a[r], w2, th[r][2]);
            }
        }
    }
    {
        float bb0 = b1[tid], bb1 = b1[256 + tid], bb2 = b1[512 + tid];
        #pragma unroll
        for (int r = 0; r < 20; ++r) {
            th[r][0] = fast_tanh(th[r][0] + bb0);
            th[r][1] = fast_tanh(th[r][1] + bb1);
            th[r][2] = fast_tanh(th[r][2] + bb2);
        }
    }

    // ---- scores: s[tt][n] = sum_j th*p2v ; shuffle + cross-wave reduce ----
    #pragma unroll
    for (int tt = 0; tt < 4; ++tt)
        #pragma unroll
        for (int n = 0; n < NW; ++n) {
            int r = tt * NW + n;
            float s = th[r][0] * p2v[tt][0];
            s = fmaf(th[r][1], p2v[tt][1], s);
            s = fmaf(th[r][2], p2v[tt][2], s);
            #pragma unroll
            for (int off = 32; off; off >>= 1) s += __shfl_xor(s, off);
            if (lane == 0) red[wave][r] = s;
        }
    __syncthreads();
    if (tid < 20) {
        float s = red[0][tid] + red[1][tid] + red[2][tid] + red[3][tid];
        sc_s[tid / NW][tid % NW] = s;
    }
    __syncthreads();

    // ---- masked softmax over N=5 ----
    if (tid < 4) {
        float v[NW]; float m = -3.0e38f;
        #pragma unroll
        for (int n = 0; n < NW; ++n) {
            float sv = (mask[(tok0 + tid) * NW + n] != 0) ? -1.0e9f : sc_s[tid][n];
            v[n] = sv; m = fmaxf(m, sv);
        }
        float sum = 0.f;
        #pragma unroll
        for (int n = 0; n < NW; ++n) { float e = expf(v[n] - m); v[n] = e; sum += e; }
        float inv = 1.0f / sum;
        #pragma unroll
        for (int n = 0; n < NW; ++n) at_s[tid][n] = v[n] * inv;
    }
    __syncthreads();   // also separates last weT reads from athT writes

    // ---- ATH (registers) -> athT view: smem[k*4 + tt], 16B rows ----
    #pragma unroll
    for (int tt = 0; tt < 4; ++tt) {
        float a0 = 0.f, a1 = 0.f, a2 = 0.f;
        #pragma unroll
        for (int n = 0; n < NW; ++n) {
            float w = at_s[tt][n];
            a0 = fmaf(w, th[tt * NW + n][0], a0);
            a1 = fmaf(w, th[tt * NW + n][1], a1);
            a2 = fmaf(w, th[tt * NW + n][2], a2);
        }
        smem[(0 * 256 + tid) * 4 + tt] = a0;
        smem[(1 * 256 + tid) * 4 + tt] = a1;
        smem[(2 * 256 + tid) * 4 + tt] = a2;
    }
    __syncthreads();

    // ---- GEMM2: acc[t][c] = sum_k athT[k][t] * W2[k][j] ----
    float acc[4][3];
    #pragma unroll
    for (int t = 0; t < 4; ++t) { acc[t][0] = 0.f; acc[t][1] = 0.f; acc[t][2] = 0.f; }

    #pragma unroll 4
    for (int k = 0; k < HID; ++k) {
        float4 a4 = *reinterpret_cast<const float4*>(&smem[k * 4]);
        float w0 = W2[(size_t)k * HID + tid];
        float w1 = W2[(size_t)k * HID + 256 + tid];
        float w2 = W2[(size_t)k * HID + 512 + tid];
        acc[0][0] = fmaf(a4.x, w0, acc[0][0]); acc[0][1] = fmaf(a4.x, w1, acc[0][1]); acc[0][2] = fmaf(a4.x, w2, acc[0][2]);
        acc[1][0] = fmaf(a4.y, w0, acc[1][0]); acc[1][1] = fmaf(a4.y, w1, acc[1][1]); acc[1][2] = fmaf(a4.y, w2, acc[1][2]);
        acc[2][0] = fmaf(a4.z, w0, acc[2][0]); acc[2][1] = fmaf(a4.z, w1, acc[2][1]); acc[2][2] = fmaf(a4.z, w2, acc[2][2]);
        acc[3][0] = fmaf(a4.w, w0, acc[3][0]); acc[3][1] = fmaf(a4.w, w1, acc[3][1]); acc[3][2] = fmaf(a4.w, w2, acc[3][2]);
    }

    // ---- + b2 + LO residual ----
    float v[4][3];
    {
        float bb0 = b2[tid], bb1 = b2[256 + tid], bb2 = b2[512 + tid];
        #pragma unroll
        for (int t = 0; t < 4; ++t) {
            v[t][0] = acc[t][0] + bb0 + LO[(tok0 + t) * HID + tid];
            v[t][1] = acc[t][1] + bb1 + LO[(tok0 + t) * HID + 256 + tid];
            v[t][2] = acc[t][2] + bb2 + LO[(tok0 + t) * HID + 512 + tid];
        }
    }

    // ---- LayerNorm reductions (sum, sumsq per token) ----
    #pragma unroll
    for (int t = 0; t < 4; ++t) {
        float s = v[t][0] + v[t][1] + v[t][2];
        float q = v[t][0] * v[t][0];
        q = fmaf(v[t][1], v[t][1], q);
        q = fmaf(v[t][2], v[t][2], q);
        #pragma unroll
        for (int off = 32; off; off >>= 1) { s += __shfl_xor(s, off); q += __shfl_xor(q, off); }
        if (lane == 0) { red[wave][t] = s; red[wave][4 + t] = q; }
    }
    __syncthreads();
    if (tid < 4) {
        float S = red[0][tid] + red[1][tid] + red[2][tid] + red[3][tid];
        float Q = red[0][4 + tid] + red[1][4 + tid] + red[2][4 + tid] + red[3][4 + tid];
        float mu = S * (1.0f / HID);
        float var = Q * (1.0f / HID) - mu * mu;
        mus[tid] = mu;
        rss[tid] = rsqrtf(var + 1e-12f);
    }
    __syncthreads();

    {
        float g0 = gamma[tid], g1 = gamma[256 + tid], g2 = gamma[512 + tid];
        float e0 = beta[tid],  e1 = beta[256 + tid],  e2 = beta[512 + tid];
        #pragma unroll
        for (int t = 0; t < 4; ++t) {
            float mu = mus[t], rs = rss[t];
            out[(tok0 + t) * HID + tid]       = (v[t][0] - mu) * rs * g0 + e0;
            out[(tok0 + t) * HID + 256 + tid] = (v[t][1] - mu) * rs * g1 + e1;
            out[(tok0 + t) * HID + 512 + tid] = (v[t][2] - mu) * rs * g2 + e2;
        }
    }
}

// ---------------------------------------------------------------------------
extern "C" void kernel_launch(void* const* d_in, const int* in_sizes, int n_in,
                              void* d_out, int out_size, void* d_ws, size_t ws_size,
                              hipStream_t stream)
{
    const float* LO    = (const float*)d_in[0];  // [16,512,768]
    const float* WE    = (const float*)d_in[1];  // [16,512,5,200]
    const int*   mask  = (const int*)  d_in[2];  // [16,512,5]
    const float* W1    = (const float*)d_in[3];  // [200,768]
    const float* b1    = (const float*)d_in[4];  // [768]
    const float* W2    = (const float*)d_in[5];  // [768,768]
    const float* b2    = (const float*)d_in[6];  // [768]
    const float* attnW = (const float*)d_in[7];  // [768,768]
    const float* gamma = (const float*)d_in[8];  // [768]
    const float* beta  = (const float*)d_in[9];  // [768]
    float* out = (float*)d_out;                  // [16,512,768]

    const int T = 16 * 512;  // 8192 tokens

    // workspace (floats): P2 [T,768] | G [768,768]   (~27.6 MB)
    float* P2 = (float*)d_ws;
    float* G  = P2 + (size_t)T * HID;

    gw_kernel<<<(HID / 64) * (HID / 64), 256, 0, stream>>>(attnW, W2, G);
    proj_kernel<8><<<T / 8, 256, 0, stream>>>(LO, G, P2);
    fused_kernel<<<T / 4, 256, 0, stream>>>(WE, W1, b1, W2, b2, LO, P2, mask, gamma, beta, out);
}